// Round 5
// baseline (613.764 us; speedup 1.0000x reference)
//
#include <hip/hip_runtime.h>

typedef _Float16 h16;
typedef __attribute__((ext_vector_type(4))) _Float16 h16x4;
typedef __attribute__((ext_vector_type(8))) _Float16 h16x8;
typedef __attribute__((ext_vector_type(4))) float f32x4;

#define NQD 4194304L   // 16384 * 256
#define NROWS 16384L
#define NKK 4096L

static __device__ __forceinline__ f32x4 mfma16(h16x8 a, h16x8 b, f32x4 c) {
  return __builtin_amdgcn_mfma_f32_16x16x32_f16(a, b, c, 0, 0, 0);
}

// ---------------- cast 6 weight matrices fp32 -> f16 ----------------
__global__ void cast_weights(const float* __restrict__ w0, const float* __restrict__ w1,
                             const float* __restrict__ w2, const float* __restrict__ w3,
                             const float* __restrict__ w4, const float* __restrict__ w5,
                             h16* __restrict__ dst) {
  int wi = blockIdx.y;
  const float* src = wi == 0 ? w0 : wi == 1 ? w1 : wi == 2 ? w2 : wi == 3 ? w3 : wi == 4 ? w4 : w5;
  int c = blockIdx.x * 256 + threadIdx.x;
  float4 v = ((const float4*)src)[c];
  h16x4 h = {(h16)v.x, (h16)v.y, (h16)v.z, (h16)v.w};
  *(h16x4*)&dst[(long)wi * 65536 + (long)c * 4] = h;
}

// ---------------- fused Q/K/V projection: z picks operand set ----------------
// grid(128, 4, 3), block 256. Tile 128x64, BK=64.
// z==2 (V): output transposed vT[b][d][k] via LDS restage, coalesced h16x8 stores.
__global__ __launch_bounds__(256) void qkv_proj(const float* __restrict__ x,
                                                const float* __restrict__ qry,
                                                const h16* __restrict__ wh,
                                                const float* __restrict__ bq,
                                                const float* __restrict__ bk,
                                                const float* __restrict__ bv,
                                                h16* __restrict__ qh,
                                                h16* __restrict__ kh,
                                                h16* __restrict__ vT) {
  const int z = blockIdx.z;
  const float* A = (z == 0) ? qry : x;
  const h16* W = wh + (long)z * 65536;
  const float* bias = (z == 0) ? bq : (z == 1) ? bk : bv;
  h16* outH = (z == 0) ? qh : (z == 1) ? kh : nullptr;
  h16* outT = (z == 2) ? vT : nullptr;

  __shared__ h16 smem[128 * 72 + 64 * 72];
  h16 (*As)[72] = (h16(*)[72])smem;
  h16 (*Bs)[72] = (h16(*)[72])(smem + 128 * 72);
  const int tid = threadIdx.x;
  const int wave = tid >> 6, lane = tid & 63;
  const int quad = lane >> 4, l16 = lane & 15;
  const long arow0 = (long)blockIdx.x * 128;
  const int bn = blockIdx.y;
  f32x4 acc[2][4] = {};
  for (int k0 = 0; k0 < 256; k0 += 64) {
    #pragma unroll
    for (int it = 0; it < 8; ++it) {
      int c = it * 256 + tid;
      int r = c >> 4, c4 = (c & 15) * 4;
      float4 v = *(const float4*)&A[(arow0 + r) * 256 + k0 + c4];
      h16x4 h = {(h16)v.x, (h16)v.y, (h16)v.z, (h16)v.w};
      *(h16x4*)&As[r][c4] = h;
    }
    #pragma unroll
    for (int it = 0; it < 2; ++it) {
      int c = it * 256 + tid;
      int r = c >> 3, c8 = (c & 7) * 8;
      *(h16x8*)&Bs[r][c8] = *(const h16x8*)&W[(long)(bn * 64 + r) * 256 + k0 + c8];
    }
    __syncthreads();
    #pragma unroll
    for (int ks = 0; ks < 64; ks += 32) {
      h16x8 a[2], b[4];
      #pragma unroll
      for (int mi = 0; mi < 2; ++mi)
        a[mi] = *(const h16x8*)&As[wave * 32 + mi * 16 + l16][ks + quad * 8];
      #pragma unroll
      for (int ni = 0; ni < 4; ++ni)
        b[ni] = *(const h16x8*)&Bs[ni * 16 + l16][ks + quad * 8];
      #pragma unroll
      for (int mi = 0; mi < 2; ++mi)
        #pragma unroll
        for (int ni = 0; ni < 4; ++ni)
          acc[mi][ni] = mfma16(a[mi], b[ni], acc[mi][ni]);
    }
    __syncthreads();
  }
  if (outH) {
    #pragma unroll
    for (int mi = 0; mi < 2; ++mi) {
      #pragma unroll
      for (int ni = 0; ni < 4; ++ni) {
        int n = bn * 64 + ni * 16 + l16;
        float bv_ = bias[n];
        #pragma unroll
        for (int i = 0; i < 4; ++i) {
          long m = arow0 + wave * 32 + mi * 16 + quad * 4 + i;
          outH[m * 256 + n] = (h16)(acc[mi][ni][i] + bv_);
        }
      }
    }
  } else {
    // restage transposed: stg[d(64)][k(128)], stride 136 to spread banks
    h16* stg = smem;
    #pragma unroll
    for (int mi = 0; mi < 2; ++mi) {
      #pragma unroll
      for (int ni = 0; ni < 4; ++ni) {
        int dl = ni * 16 + l16;
        float bv_ = bias[bn * 64 + dl];
        int mlb = wave * 32 + mi * 16 + quad * 4;
        h16x4 hv = {(h16)(acc[mi][ni][0] + bv_), (h16)(acc[mi][ni][1] + bv_),
                    (h16)(acc[mi][ni][2] + bv_), (h16)(acc[mi][ni][3] + bv_)};
        *(h16x4*)&stg[dl * 136 + mlb] = hv;
      }
    }
    __syncthreads();
    const int bb = (int)(arow0 >> 12);
    const long kb = arow0 & 4095;
    #pragma unroll
    for (int p = 0; p < 4; ++p) {
      int d = p * 16 + (tid >> 4);
      int c = (tid & 15) * 8;
      h16x8 v = *(const h16x8*)&stg[d * 136 + c];
      *(h16x8*)&outT[((long)bb * 256 + bn * 64 + d) * 4096 + kb + c] = v;
    }
  }
}

// ---------------- plain 256-K GEMM for MLP ----------------
__global__ __launch_bounds__(256) void gemm256(const h16* __restrict__ A,
                                               const h16* __restrict__ W,
                                               const float* __restrict__ bias,
                                               h16* __restrict__ outH,
                                               float* __restrict__ outF) {
  __shared__ h16 As[128][72];
  __shared__ h16 Bs[64][72];
  const int tid = threadIdx.x;
  const int wave = tid >> 6, lane = tid & 63;
  const int quad = lane >> 4, l16 = lane & 15;
  const long arow0 = (long)blockIdx.x * 128;
  const int bn = blockIdx.y;
  f32x4 acc[2][4] = {};
  for (int k0 = 0; k0 < 256; k0 += 64) {
    #pragma unroll
    for (int it = 0; it < 4; ++it) {
      int c = it * 256 + tid;
      int r = c >> 3, c8 = (c & 7) * 8;
      *(h16x8*)&As[r][c8] = *(const h16x8*)&A[(arow0 + r) * 256 + k0 + c8];
    }
    #pragma unroll
    for (int it = 0; it < 2; ++it) {
      int c = it * 256 + tid;
      int r = c >> 3, c8 = (c & 7) * 8;
      *(h16x8*)&Bs[r][c8] = *(const h16x8*)&W[(long)(bn * 64 + r) * 256 + k0 + c8];
    }
    __syncthreads();
    #pragma unroll
    for (int ks = 0; ks < 64; ks += 32) {
      h16x8 a[2], b[4];
      #pragma unroll
      for (int mi = 0; mi < 2; ++mi)
        a[mi] = *(const h16x8*)&As[wave * 32 + mi * 16 + l16][ks + quad * 8];
      #pragma unroll
      for (int ni = 0; ni < 4; ++ni)
        b[ni] = *(const h16x8*)&Bs[ni * 16 + l16][ks + quad * 8];
      #pragma unroll
      for (int mi = 0; mi < 2; ++mi)
        #pragma unroll
        for (int ni = 0; ni < 4; ++ni)
          acc[mi][ni] = mfma16(a[mi], b[ni], acc[mi][ni]);
    }
    __syncthreads();
  }
  #pragma unroll
  for (int mi = 0; mi < 2; ++mi) {
    #pragma unroll
    for (int ni = 0; ni < 4; ++ni) {
      int n = bn * 64 + ni * 16 + l16;
      float bv = bias[n];
      #pragma unroll
      for (int i = 0; i < 4; ++i) {
        long m = arow0 + wave * 32 + mi * 16 + quad * 4 + i;
        float v = fmaxf(acc[mi][ni][i] + bv, 0.0f);
        if (outH) outH[m * 256 + n] = (h16)v;
        if (outF) outF[m * 256 + n] = v;
      }
    }
  }
}

// ---------------- scores: S = qk^T/16 (raw), + per-tile row stats ----------------
// grid(32, 32, 4), block 256. Tile 128x128, BK=64.
// f16 S is written via LDS restage -> coalesced h16x8 stores.
__global__ __launch_bounds__(256) void gemm_scores(const h16* __restrict__ qh,
                                                   const h16* __restrict__ kh,
                                                   float2* __restrict__ stats,
                                                   h16* __restrict__ Sh,
                                                   float* __restrict__ Sf) {
  __shared__ h16 smem[128 * 72 * 2];
  h16 (*As)[72] = (h16(*)[72])smem;
  h16 (*Bs)[72] = (h16(*)[72])(smem + 128 * 72);
  const int tid = threadIdx.x;
  const int wave = tid >> 6, lane = tid & 63;
  const int quad = lane >> 4, l16 = lane & 15;
  const int bm = blockIdx.x, bn = blockIdx.y, b = blockIdx.z;
  const h16* Aq = qh + (long)b * 4096 * 256 + (long)bm * 128 * 256;
  const h16* Bk = kh + (long)b * 4096 * 256 + (long)bn * 128 * 256;
  f32x4 acc[2][8] = {};
  for (int k0 = 0; k0 < 256; k0 += 64) {
    #pragma unroll
    for (int it = 0; it < 4; ++it) {
      int c = it * 256 + tid;
      int r = c >> 3, c8 = (c & 7) * 8;
      *(h16x8*)&As[r][c8] = *(const h16x8*)&Aq[(long)r * 256 + k0 + c8];
      *(h16x8*)&Bs[r][c8] = *(const h16x8*)&Bk[(long)r * 256 + k0 + c8];
    }
    __syncthreads();
    #pragma unroll
    for (int ks = 0; ks < 64; ks += 32) {
      h16x8 a[2], bb[8];
      #pragma unroll
      for (int mi = 0; mi < 2; ++mi)
        a[mi] = *(const h16x8*)&As[wave * 32 + mi * 16 + l16][ks + quad * 8];
      #pragma unroll
      for (int ni = 0; ni < 8; ++ni)
        bb[ni] = *(const h16x8*)&Bs[ni * 16 + l16][ks + quad * 8];
      #pragma unroll
      for (int mi = 0; mi < 2; ++mi)
        #pragma unroll
        for (int ni = 0; ni < 8; ++ni)
          acc[mi][ni] = mfma16(a[mi], bb[ni], acc[mi][ni]);
    }
    __syncthreads();
  }
  // scale
  #pragma unroll
  for (int mi = 0; mi < 2; ++mi)
    #pragma unroll
    for (int ni = 0; ni < 8; ++ni)
      #pragma unroll
      for (int i = 0; i < 4; ++i)
        acc[mi][ni][i] *= 0.0625f;
  // per-row stats: max over 128 cols, expsum relative to it
  #pragma unroll
  for (int mi = 0; mi < 2; ++mi) {
    #pragma unroll
    for (int i = 0; i < 4; ++i) {
      float mx = -1e30f;
      #pragma unroll
      for (int ni = 0; ni < 8; ++ni) mx = fmaxf(mx, acc[mi][ni][i]);
      #pragma unroll
      for (int off = 1; off < 16; off <<= 1) mx = fmaxf(mx, __shfl_xor(mx, off));
      float es = 0.0f;
      #pragma unroll
      for (int ni = 0; ni < 8; ++ni) es += __expf(acc[mi][ni][i] - mx);
      #pragma unroll
      for (int off = 1; off < 16; off <<= 1) es += __shfl_xor(es, off);
      if (l16 == 0) {
        long row = (long)b * 4096 + bm * 128 + wave * 32 + mi * 16 + quad * 4 + i;
        stats[row * 32 + bn] = make_float2(mx, es);
      }
    }
  }
  if (Sh) {
    // restage the 128x128 f16 tile in LDS (reuse GEMM smem), then coalesced write
    h16* stg = smem;   // [128][136]
    #pragma unroll
    for (int mi = 0; mi < 2; ++mi) {
      #pragma unroll
      for (int ni = 0; ni < 8; ++ni) {
        int c = ni * 16 + l16;
        #pragma unroll
        for (int i = 0; i < 4; ++i) {
          int r = wave * 32 + mi * 16 + quad * 4 + i;
          stg[r * 136 + c] = (h16)acc[mi][ni][i];
        }
      }
    }
    __syncthreads();
    const long rowbase = (long)b * 4096 + (long)bm * 128;
    const long colbase = (long)bn * 128;
    #pragma unroll
    for (int p = 0; p < 8; ++p) {
      int r = p * 16 + (tid >> 4);
      int c = (tid & 15) * 8;
      h16x8 v = *(const h16x8*)&stg[r * 136 + c];
      *(h16x8*)&Sh[(rowbase + r) * 4096 + colbase + c] = v;
    }
  } else {
    #pragma unroll
    for (int mi = 0; mi < 2; ++mi) {
      #pragma unroll
      for (int ni = 0; ni < 8; ++ni) {
        long col = (long)bn * 128 + ni * 16 + l16;
        #pragma unroll
        for (int i = 0; i < 4; ++i) {
          long row = (long)b * 4096 + bm * 128 + wave * 32 + mi * 16 + quad * 4 + i;
          Sf[row * 4096 + col] = acc[mi][ni][i];
        }
      }
    }
  }
}

// ---------------- av2 (modeA): fused rowstats + softmax + O = P @ vT^T, direct-global V ----------------
// grid(512, 2), block 256 (4 waves). Per block: M=32 rows, N=128 d-cols (ny half), K=4096.
// V is NOT LDS-staged: B-fragments load straight from vT (L2/LLC-resident, 64B segments).
// 4 blocks/CU -> 16 waves/CU in 4 independent barrier domains.
__global__ __launch_bounds__(256, 4) void gemm_av2(const h16* __restrict__ S,
                                                   const h16* __restrict__ vT,
                                                   const float2* __restrict__ stats,
                                                   float* __restrict__ attn,
                                                   h16* __restrict__ oh) {
  __shared__ h16 As[32][72];
  __shared__ h16 stg[32][136];
  __shared__ float2 rs[32];
  const int tid = threadIdx.x;
  const int wave = tid >> 6, lane = tid & 63;
  const int quad = lane >> 4, l16 = lane & 15;
  const int mb = blockIdx.x, ny = blockIdx.y;
  const long row0 = (long)mb * 32;
  const int b = mb >> 7;
  const h16* Vb = vT + (long)b * 256 * 4096 + ((long)ny * 128) * 4096;

  // ---- fused rowstats: merge 32 tile-stats per row -> (m, 1/l) for 32 rows ----
  {
    int r = tid >> 3, j = tid & 7;
    const float2* sp = stats + (row0 + r) * 32 + j * 4;
    float2 sv4[4];
    float m = -1e30f;
    #pragma unroll
    for (int t = 0; t < 4; ++t) { sv4[t] = sp[t]; m = fmaxf(m, sv4[t].x); }
    m = fmaxf(m, __shfl_xor(m, 1));
    m = fmaxf(m, __shfl_xor(m, 2));
    m = fmaxf(m, __shfl_xor(m, 4));
    float e = 0.0f;
    #pragma unroll
    for (int t = 0; t < 4; ++t) e += sv4[t].y * __expf(sv4[t].x - m);
    e += __shfl_xor(e, 1);
    e += __shfl_xor(e, 2);
    e += __shfl_xor(e, 4);
    if (j == 0) rs[r] = make_float2(m, 1.0f / e);
  }
  __syncthreads();

  const int sr = tid >> 3, sc = (tid & 7) * 8;   // 8 threads/row, h16x8 chunk
  const long srow = row0 + sr;
  const float2 st = rs[sr];
  const h16* Srow = S + srow * 4096;
  float* Arow = attn + srow * 4096;

  f32x4 acc[2][2] = {};
  h16x8 sv = *(const h16x8*)&Srow[sc];          // prologue S prefetch

  for (int k0 = 0; k0 < 4096; k0 += 64) {
    // ---- stage P: p = exp(s-m)*invl; ny==0 writes attn (nontemporal) ----
    float p[8];
    #pragma unroll
    for (int e = 0; e < 8; ++e) p[e] = __expf((float)sv[e] - st.x) * st.y;
    if (ny == 0) {
      f32x4 w0 = {p[0], p[1], p[2], p[3]}, w1 = {p[4], p[5], p[6], p[7]};
      __builtin_nontemporal_store(w0, (f32x4*)&Arow[k0 + sc]);
      __builtin_nontemporal_store(w1, (f32x4*)&Arow[k0 + sc + 4]);
    }
    h16x8 ph = {(h16)p[0], (h16)p[1], (h16)p[2], (h16)p[3],
                (h16)p[4], (h16)p[5], (h16)p[6], (h16)p[7]};
    *(h16x8*)&As[sr][sc] = ph;
    // ---- B fragments: direct global loads (issued before barrier, used after) ----
    h16x8 bb[2][2];
    #pragma unroll
    for (int ks2 = 0; ks2 < 2; ++ks2)
      #pragma unroll
      for (int ni = 0; ni < 2; ++ni)
        bb[ks2][ni] = *(const h16x8*)&Vb[(long)(wave * 32 + ni * 16 + l16) * 4096 + k0 + ks2 * 32 + quad * 8];
    // ---- S prefetch for next tile ----
    int kn = k0 + 64;
    if (kn < 4096) sv = *(const h16x8*)&Srow[kn + sc];
    __syncthreads();
    #pragma unroll
    for (int ks2 = 0; ks2 < 2; ++ks2) {
      h16x8 a0 = *(const h16x8*)&As[l16][ks2 * 32 + quad * 8];
      h16x8 a1 = *(const h16x8*)&As[16 + l16][ks2 * 32 + quad * 8];
      acc[0][0] = mfma16(a0, bb[ks2][0], acc[0][0]);
      acc[0][1] = mfma16(a0, bb[ks2][1], acc[0][1]);
      acc[1][0] = mfma16(a1, bb[ks2][0], acc[1][0]);
      acc[1][1] = mfma16(a1, bb[ks2][1], acc[1][1]);
    }
    __syncthreads();
  }
  // ---- epilogue: restage 32x128 O tile, coalesced h16x8 stores ----
  #pragma unroll
  for (int mi = 0; mi < 2; ++mi) {
    #pragma unroll
    for (int ni = 0; ni < 2; ++ni) {
      int col = wave * 32 + ni * 16 + l16;
      #pragma unroll
      for (int i = 0; i < 4; ++i)
        stg[mi * 16 + quad * 4 + i][col] = (h16)acc[mi][ni][i];
    }
  }
  __syncthreads();
  #pragma unroll
  for (int p = 0; p < 2; ++p) {
    int r = tid >> 3;
    int c = (tid & 7) * 8 + p * 64;
    h16x8 v = *(const h16x8*)&stg[r][c];
    *(h16x8*)&oh[(row0 + r) * 256 + ny * 128 + c] = v;
  }
}

// ---------------- av (modeB fallback, fp32 S in attn buffer, in-place) ----------------
// grid(256), block 512 (8 waves). Tile M=64, N=256, BK=64.
template <typename TS>
__global__ __launch_bounds__(512, 2) void gemm_av(const TS* __restrict__ S,
                                                  const h16* __restrict__ vT,
                                                  const float2* __restrict__ stats,
                                                  float* __restrict__ attn,
                                                  h16* __restrict__ oh) {
  __shared__ h16 As[64][72];
  __shared__ h16 Bs[256][72];
  __shared__ float2 rs[64];
  const int tid = threadIdx.x;
  const int wave = tid >> 6, lane = tid & 63;
  const int quad = lane >> 4, l16 = lane & 15;
  const int mb = blockIdx.x;
  const long row0 = (long)mb * 64;
  const int b = mb >> 6;
  const h16* Vb = vT + (long)b * 256 * 4096;

  {
    int r = tid >> 3, j = tid & 7;
    const float2* sp = stats + (row0 + r) * 32 + j * 4;
    float2 sv4[4];
    float m = -1e30f;
    #pragma unroll
    for (int t = 0; t < 4; ++t) { sv4[t] = sp[t]; m = fmaxf(m, sv4[t].x); }
    m = fmaxf(m, __shfl_xor(m, 1));
    m = fmaxf(m, __shfl_xor(m, 2));
    m = fmaxf(m, __shfl_xor(m, 4));
    float e = 0.0f;
    #pragma unroll
    for (int t = 0; t < 4; ++t) e += sv4[t].y * __expf(sv4[t].x - m);
    e += __shfl_xor(e, 1);
    e += __shfl_xor(e, 2);
    e += __shfl_xor(e, 4);
    if (j == 0) rs[r] = make_float2(m, 1.0f / e);
  }
  __syncthreads();

  const int sr = tid >> 3, sc = (tid & 7) * 8;
  const long srow = row0 + sr;
  const float2 st = rs[sr];
  const TS* Srow = S + srow * 4096;
  float* Arow = attn + srow * 4096;
  const int vd = tid >> 3;

  f32x4 acc[4][2] = {};

  h16x8 sv; float4 sa, sb;
  h16x8 bv0, bv1, bv2, bv3;
  if constexpr (sizeof(TS) == 2) {
    sv = *(const h16x8*)&Srow[sc];
  } else {
    sa = *(const float4*)&Srow[sc];
    sb = *(const float4*)&Srow[sc + 4];
  }
  bv0 = *(const h16x8*)&Vb[(long)(vd)       * 4096 + sc];
  bv1 = *(const h16x8*)&Vb[(long)(vd + 64)  * 4096 + sc];
  bv2 = *(const h16x8*)&Vb[(long)(vd + 128) * 4096 + sc];
  bv3 = *(const h16x8*)&Vb[(long)(vd + 192) * 4096 + sc];

  for (int k0 = 0; k0 < 4096; k0 += 64) {
    float p[8];
    if constexpr (sizeof(TS) == 2) {
      #pragma unroll
      for (int e = 0; e < 8; ++e) p[e] = __expf((float)sv[e] - st.x) * st.y;
    } else {
      p[0] = __expf(sa.x - st.x) * st.y; p[1] = __expf(sa.y - st.x) * st.y;
      p[2] = __expf(sa.z - st.x) * st.y; p[3] = __expf(sa.w - st.x) * st.y;
      p[4] = __expf(sb.x - st.x) * st.y; p[5] = __expf(sb.y - st.x) * st.y;
      p[6] = __expf(sb.z - st.x) * st.y; p[7] = __expf(sb.w - st.x) * st.y;
    }
    f32x4 w0 = {p[0], p[1], p[2], p[3]}, w1 = {p[4], p[5], p[6], p[7]};
    __builtin_nontemporal_store(w0, (f32x4*)&Arow[k0 + sc]);
    __builtin_nontemporal_store(w1, (f32x4*)&Arow[k0 + sc + 4]);
    h16x8 ph = {(h16)p[0], (h16)p[1], (h16)p[2], (h16)p[3],
                (h16)p[4], (h16)p[5], (h16)p[6], (h16)p[7]};
    *(h16x8*)&As[sr][sc] = ph;
    *(h16x8*)&Bs[vd][sc]       = bv0;
    *(h16x8*)&Bs[vd + 64][sc]  = bv1;
    *(h16x8*)&Bs[vd + 128][sc] = bv2;
    *(h16x8*)&Bs[vd + 192][sc] = bv3;
    int kn = k0 + 64;
    if (kn < 4096) {
      if constexpr (sizeof(TS) == 2) {
        sv = *(const h16x8*)&Srow[kn + sc];
      } else {
        sa = *(const float4*)&Srow[kn + sc];
        sb = *(const float4*)&Srow[kn + sc + 4];
      }
      bv0 = *(const h16x8*)&Vb[(long)(vd)       * 4096 + kn + sc];
      bv1 = *(const h16x8*)&Vb[(long)(vd + 64)  * 4096 + kn + sc];
      bv2 = *(const h16x8*)&Vb[(long)(vd + 128) * 4096 + kn + sc];
      bv3 = *(const h16x8*)&Vb[(long)(vd + 192) * 4096 + kn + sc];
    }
    __syncthreads();
    #pragma unroll
    for (int ks = 0; ks < 64; ks += 32) {
      h16x8 a[4], bbv[2];
      #pragma unroll
      for (int mi = 0; mi < 4; ++mi)
        a[mi] = *(const h16x8*)&As[mi * 16 + l16][ks + quad * 8];
      #pragma unroll
      for (int ni = 0; ni < 2; ++ni)
        bbv[ni] = *(const h16x8*)&Bs[wave * 32 + ni * 16 + l16][ks + quad * 8];
      #pragma unroll
      for (int mi = 0; mi < 4; ++mi)
        #pragma unroll
        for (int ni = 0; ni < 2; ++ni)
          acc[mi][ni] = mfma16(a[mi], bbv[ni], acc[mi][ni]);
    }
    __syncthreads();
  }
  h16* stg = &Bs[0][0];
  const int SW = 264;
  #pragma unroll
  for (int mi = 0; mi < 4; ++mi) {
    #pragma unroll
    for (int ni = 0; ni < 2; ++ni) {
      int col = wave * 32 + ni * 16 + l16;
      #pragma unroll
      for (int i = 0; i < 4; ++i) {
        int r = mi * 16 + quad * 4 + i;
        stg[r * SW + col] = (h16)acc[mi][ni][i];
      }
    }
  }
  __syncthreads();
  #pragma unroll
  for (int p = 0; p < 4; ++p) {
    int r = tid >> 3;
    int c = (tid & 7) * 8 + p * 64;
    h16x8 v = *(const h16x8*)&stg[r * SW + c];
    *(h16x8*)&oh[(row0 + r) * 256 + c] = v;
  }
}

extern "C" void kernel_launch(void* const* d_in, const int* in_sizes, int n_in,
                              void* d_out, int out_size, void* d_ws, size_t ws_size,
                              hipStream_t stream) {
  (void)in_sizes; (void)n_in; (void)out_size;
  const float* x   = (const float*)d_in[0];
  const float* qry = (const float*)d_in[1];
  const float* Wq  = (const float*)d_in[2];  const float* bq = (const float*)d_in[3];
  const float* Wk  = (const float*)d_in[4];  const float* bk = (const float*)d_in[5];
  const float* Wv  = (const float*)d_in[6];  const float* bv = (const float*)d_in[7];
  const float* W1  = (const float*)d_in[8];  const float* b1 = (const float*)d_in[9];
  const float* W2  = (const float*)d_in[10]; const float* b2 = (const float*)d_in[11];
  const float* W3  = (const float*)d_in[12]; const float* b3 = (const float*)d_in[13];

  float* outH = (float*)d_out;
  float* attn = outH + NQD;

  char* w = (char*)d_ws;
  h16* qh = (h16*)w;
  h16* kh = qh + NQD;
  h16* vT = kh + NQD;
  h16* oh = vT + NQD;
  h16* h1 = oh + NQD;
  h16* h2 = h1 + NQD;
  h16* wh = h2 + NQD;                               // 6 x 65536 h16
  size_t off_rs   = (size_t)(6 * NQD + 6 * 65536) * 2;   // 51,118,080
  size_t BASE     = off_rs + NROWS * 8;                  // 51,249,152
  size_t statsB   = NROWS * 32 * 8;                      // 4 MiB
  size_t ShB      = NROWS * NKK * 2;                     // 128 MiB

  bool modeA = ws_size >= BASE + statsB + ShB;
  bool modeB = !modeA && ws_size >= BASE + statsB;

  float2* stats = (modeA || modeB) ? (float2*)(w + BASE) : (float2*)h1;
  h16*    Sh    = modeA ? (h16*)(w + BASE + statsB) : nullptr;

  cast_weights<<<dim3(64, 6), 256, 0, stream>>>(Wq, Wk, Wv, W1, W2, W3, wh);
  qkv_proj<<<dim3(128, 4, 3), 256, 0, stream>>>(x, qry, wh, bq, bk, bv, qh, kh, vT);
  gemm_scores<<<dim3(32, 32, 4), 256, 0, stream>>>(qh, kh, stats, Sh, modeA ? nullptr : attn);
  if (modeA)
    gemm_av2<<<dim3(512, 2), 256, 0, stream>>>(Sh, vT, stats, attn, oh);
  else
    gemm_av<float><<<dim3(256), 512, 0, stream>>>(attn, vT, stats, attn, oh);
  gemm256<<<dim3(128, 4), 256, 0, stream>>>(oh, wh + 3 * 65536, b1, h1, nullptr);
  gemm256<<<dim3(128, 4), 256, 0, stream>>>(h1, wh + 4 * 65536, b2, h2, nullptr);
  gemm256<<<dim3(128, 4), 256, 0, stream>>>(h2, wh + 5 * 65536, b3, nullptr, outH);
}

// Round 6
// 540.039 us; speedup vs baseline: 1.1365x; 1.1365x over previous
//
#include <hip/hip_runtime.h>

typedef _Float16 h16;
typedef __attribute__((ext_vector_type(4))) _Float16 h16x4;
typedef __attribute__((ext_vector_type(8))) _Float16 h16x8;
typedef __attribute__((ext_vector_type(4))) float f32x4;

#define NQD 4194304L   // 16384 * 256
#define NROWS 16384L
#define NKK 4096L

static __device__ __forceinline__ f32x4 mfma16(h16x8 a, h16x8 b, f32x4 c) {
  return __builtin_amdgcn_mfma_f32_16x16x32_f16(a, b, c, 0, 0, 0);
}

// ---------------- cast 6 weight matrices fp32 -> f16 ----------------
__global__ void cast_weights(const float* __restrict__ w0, const float* __restrict__ w1,
                             const float* __restrict__ w2, const float* __restrict__ w3,
                             const float* __restrict__ w4, const float* __restrict__ w5,
                             h16* __restrict__ dst) {
  int wi = blockIdx.y;
  const float* src = wi == 0 ? w0 : wi == 1 ? w1 : wi == 2 ? w2 : wi == 3 ? w3 : wi == 4 ? w4 : w5;
  int c = blockIdx.x * 256 + threadIdx.x;
  float4 v = ((const float4*)src)[c];
  h16x4 h = {(h16)v.x, (h16)v.y, (h16)v.z, (h16)v.w};
  *(h16x4*)&dst[(long)wi * 65536 + (long)c * 4] = h;
}

// ---------------- fused Q/K/V projection: z picks operand set ----------------
// grid(128, 4, 3), block 256. Tile 128x64, BK=64.
// z==2 (V): output transposed vT[b][d][k] via LDS restage, coalesced h16x8 stores.
__global__ __launch_bounds__(256) void qkv_proj(const float* __restrict__ x,
                                                const float* __restrict__ qry,
                                                const h16* __restrict__ wh,
                                                const float* __restrict__ bq,
                                                const float* __restrict__ bk,
                                                const float* __restrict__ bv,
                                                h16* __restrict__ qh,
                                                h16* __restrict__ kh,
                                                h16* __restrict__ vT) {
  const int z = blockIdx.z;
  const float* A = (z == 0) ? qry : x;
  const h16* W = wh + (long)z * 65536;
  const float* bias = (z == 0) ? bq : (z == 1) ? bk : bv;
  h16* outH = (z == 0) ? qh : (z == 1) ? kh : nullptr;
  h16* outT = (z == 2) ? vT : nullptr;

  __shared__ h16 smem[128 * 72 + 64 * 72];
  h16 (*As)[72] = (h16(*)[72])smem;
  h16 (*Bs)[72] = (h16(*)[72])(smem + 128 * 72);
  const int tid = threadIdx.x;
  const int wave = tid >> 6, lane = tid & 63;
  const int quad = lane >> 4, l16 = lane & 15;
  const long arow0 = (long)blockIdx.x * 128;
  const int bn = blockIdx.y;
  f32x4 acc[2][4] = {};
  for (int k0 = 0; k0 < 256; k0 += 64) {
    #pragma unroll
    for (int it = 0; it < 8; ++it) {
      int c = it * 256 + tid;
      int r = c >> 4, c4 = (c & 15) * 4;
      float4 v = *(const float4*)&A[(arow0 + r) * 256 + k0 + c4];
      h16x4 h = {(h16)v.x, (h16)v.y, (h16)v.z, (h16)v.w};
      *(h16x4*)&As[r][c4] = h;
    }
    #pragma unroll
    for (int it = 0; it < 2; ++it) {
      int c = it * 256 + tid;
      int r = c >> 3, c8 = (c & 7) * 8;
      *(h16x8*)&Bs[r][c8] = *(const h16x8*)&W[(long)(bn * 64 + r) * 256 + k0 + c8];
    }
    __syncthreads();
    #pragma unroll
    for (int ks = 0; ks < 64; ks += 32) {
      h16x8 a[2], b[4];
      #pragma unroll
      for (int mi = 0; mi < 2; ++mi)
        a[mi] = *(const h16x8*)&As[wave * 32 + mi * 16 + l16][ks + quad * 8];
      #pragma unroll
      for (int ni = 0; ni < 4; ++ni)
        b[ni] = *(const h16x8*)&Bs[ni * 16 + l16][ks + quad * 8];
      #pragma unroll
      for (int mi = 0; mi < 2; ++mi)
        #pragma unroll
        for (int ni = 0; ni < 4; ++ni)
          acc[mi][ni] = mfma16(a[mi], b[ni], acc[mi][ni]);
    }
    __syncthreads();
  }
  if (outH) {
    #pragma unroll
    for (int mi = 0; mi < 2; ++mi) {
      #pragma unroll
      for (int ni = 0; ni < 4; ++ni) {
        int n = bn * 64 + ni * 16 + l16;
        float bv_ = bias[n];
        #pragma unroll
        for (int i = 0; i < 4; ++i) {
          long m = arow0 + wave * 32 + mi * 16 + quad * 4 + i;
          outH[m * 256 + n] = (h16)(acc[mi][ni][i] + bv_);
        }
      }
    }
  } else {
    // restage transposed: stg[d(64)][k(128)], stride 136 to spread banks
    h16* stg = smem;
    #pragma unroll
    for (int mi = 0; mi < 2; ++mi) {
      #pragma unroll
      for (int ni = 0; ni < 4; ++ni) {
        int dl = ni * 16 + l16;
        float bv_ = bias[bn * 64 + dl];
        int mlb = wave * 32 + mi * 16 + quad * 4;
        h16x4 hv = {(h16)(acc[mi][ni][0] + bv_), (h16)(acc[mi][ni][1] + bv_),
                    (h16)(acc[mi][ni][2] + bv_), (h16)(acc[mi][ni][3] + bv_)};
        *(h16x4*)&stg[dl * 136 + mlb] = hv;
      }
    }
    __syncthreads();
    const int bb = (int)(arow0 >> 12);
    const long kb = arow0 & 4095;
    #pragma unroll
    for (int p = 0; p < 4; ++p) {
      int d = p * 16 + (tid >> 4);
      int c = (tid & 15) * 8;
      h16x8 v = *(const h16x8*)&stg[d * 136 + c];
      *(h16x8*)&outT[((long)bb * 256 + bn * 64 + d) * 4096 + kb + c] = v;
    }
  }
}

// ---------------- plain 256-K GEMM for MLP ----------------
__global__ __launch_bounds__(256) void gemm256(const h16* __restrict__ A,
                                               const h16* __restrict__ W,
                                               const float* __restrict__ bias,
                                               h16* __restrict__ outH,
                                               float* __restrict__ outF) {
  __shared__ h16 As[128][72];
  __shared__ h16 Bs[64][72];
  const int tid = threadIdx.x;
  const int wave = tid >> 6, lane = tid & 63;
  const int quad = lane >> 4, l16 = lane & 15;
  const long arow0 = (long)blockIdx.x * 128;
  const int bn = blockIdx.y;
  f32x4 acc[2][4] = {};
  for (int k0 = 0; k0 < 256; k0 += 64) {
    #pragma unroll
    for (int it = 0; it < 4; ++it) {
      int c = it * 256 + tid;
      int r = c >> 3, c8 = (c & 7) * 8;
      *(h16x8*)&As[r][c8] = *(const h16x8*)&A[(arow0 + r) * 256 + k0 + c8];
    }
    #pragma unroll
    for (int it = 0; it < 2; ++it) {
      int c = it * 256 + tid;
      int r = c >> 3, c8 = (c & 7) * 8;
      *(h16x8*)&Bs[r][c8] = *(const h16x8*)&W[(long)(bn * 64 + r) * 256 + k0 + c8];
    }
    __syncthreads();
    #pragma unroll
    for (int ks = 0; ks < 64; ks += 32) {
      h16x8 a[2], b[4];
      #pragma unroll
      for (int mi = 0; mi < 2; ++mi)
        a[mi] = *(const h16x8*)&As[wave * 32 + mi * 16 + l16][ks + quad * 8];
      #pragma unroll
      for (int ni = 0; ni < 4; ++ni)
        b[ni] = *(const h16x8*)&Bs[ni * 16 + l16][ks + quad * 8];
      #pragma unroll
      for (int mi = 0; mi < 2; ++mi)
        #pragma unroll
        for (int ni = 0; ni < 4; ++ni)
          acc[mi][ni] = mfma16(a[mi], b[ni], acc[mi][ni]);
    }
    __syncthreads();
  }
  #pragma unroll
  for (int mi = 0; mi < 2; ++mi) {
    #pragma unroll
    for (int ni = 0; ni < 4; ++ni) {
      int n = bn * 64 + ni * 16 + l16;
      float bv = bias[n];
      #pragma unroll
      for (int i = 0; i < 4; ++i) {
        long m = arow0 + wave * 32 + mi * 16 + quad * 4 + i;
        float v = fmaxf(acc[mi][ni][i] + bv, 0.0f);
        if (outH) outH[m * 256 + n] = (h16)v;
        if (outF) outF[m * 256 + n] = v;
      }
    }
  }
}

// ---------------- scores: S = qk^T/16 (raw), + per-tile row stats ----------------
// grid(32, 32, 4), block 256. Tile 128x128, BK=64.
// f16 S is written via LDS restage -> coalesced h16x8 stores.
__global__ __launch_bounds__(256) void gemm_scores(const h16* __restrict__ qh,
                                                   const h16* __restrict__ kh,
                                                   float2* __restrict__ stats,
                                                   h16* __restrict__ Sh,
                                                   float* __restrict__ Sf) {
  __shared__ h16 smem[128 * 72 * 2];
  h16 (*As)[72] = (h16(*)[72])smem;
  h16 (*Bs)[72] = (h16(*)[72])(smem + 128 * 72);
  const int tid = threadIdx.x;
  const int wave = tid >> 6, lane = tid & 63;
  const int quad = lane >> 4, l16 = lane & 15;
  const int bm = blockIdx.x, bn = blockIdx.y, b = blockIdx.z;
  const h16* Aq = qh + (long)b * 4096 * 256 + (long)bm * 128 * 256;
  const h16* Bk = kh + (long)b * 4096 * 256 + (long)bn * 128 * 256;
  f32x4 acc[2][8] = {};
  for (int k0 = 0; k0 < 256; k0 += 64) {
    #pragma unroll
    for (int it = 0; it < 4; ++it) {
      int c = it * 256 + tid;
      int r = c >> 3, c8 = (c & 7) * 8;
      *(h16x8*)&As[r][c8] = *(const h16x8*)&Aq[(long)r * 256 + k0 + c8];
      *(h16x8*)&Bs[r][c8] = *(const h16x8*)&Bk[(long)r * 256 + k0 + c8];
    }
    __syncthreads();
    #pragma unroll
    for (int ks = 0; ks < 64; ks += 32) {
      h16x8 a[2], bb[8];
      #pragma unroll
      for (int mi = 0; mi < 2; ++mi)
        a[mi] = *(const h16x8*)&As[wave * 32 + mi * 16 + l16][ks + quad * 8];
      #pragma unroll
      for (int ni = 0; ni < 8; ++ni)
        bb[ni] = *(const h16x8*)&Bs[ni * 16 + l16][ks + quad * 8];
      #pragma unroll
      for (int mi = 0; mi < 2; ++mi)
        #pragma unroll
        for (int ni = 0; ni < 8; ++ni)
          acc[mi][ni] = mfma16(a[mi], bb[ni], acc[mi][ni]);
    }
    __syncthreads();
  }
  // scale
  #pragma unroll
  for (int mi = 0; mi < 2; ++mi)
    #pragma unroll
    for (int ni = 0; ni < 8; ++ni)
      #pragma unroll
      for (int i = 0; i < 4; ++i)
        acc[mi][ni][i] *= 0.0625f;
  // per-row stats: max over 128 cols, expsum relative to it
  #pragma unroll
  for (int mi = 0; mi < 2; ++mi) {
    #pragma unroll
    for (int i = 0; i < 4; ++i) {
      float mx = -1e30f;
      #pragma unroll
      for (int ni = 0; ni < 8; ++ni) mx = fmaxf(mx, acc[mi][ni][i]);
      #pragma unroll
      for (int off = 1; off < 16; off <<= 1) mx = fmaxf(mx, __shfl_xor(mx, off));
      float es = 0.0f;
      #pragma unroll
      for (int ni = 0; ni < 8; ++ni) es += __expf(acc[mi][ni][i] - mx);
      #pragma unroll
      for (int off = 1; off < 16; off <<= 1) es += __shfl_xor(es, off);
      if (l16 == 0) {
        long row = (long)b * 4096 + bm * 128 + wave * 32 + mi * 16 + quad * 4 + i;
        stats[row * 32 + bn] = make_float2(mx, es);
      }
    }
  }
  if (Sh) {
    // restage the 128x128 f16 tile in LDS (reuse GEMM smem), then coalesced write
    h16* stg = smem;   // [128][136]
    #pragma unroll
    for (int mi = 0; mi < 2; ++mi) {
      #pragma unroll
      for (int ni = 0; ni < 8; ++ni) {
        int c = ni * 16 + l16;
        #pragma unroll
        for (int i = 0; i < 4; ++i) {
          int r = wave * 32 + mi * 16 + quad * 4 + i;
          stg[r * 136 + c] = (h16)acc[mi][ni][i];
        }
      }
    }
    __syncthreads();
    const long rowbase = (long)b * 4096 + (long)bm * 128;
    const long colbase = (long)bn * 128;
    #pragma unroll
    for (int p = 0; p < 8; ++p) {
      int r = p * 16 + (tid >> 4);
      int c = (tid & 15) * 8;
      h16x8 v = *(const h16x8*)&stg[r * 136 + c];
      *(h16x8*)&Sh[(rowbase + r) * 4096 + colbase + c] = v;
    }
  } else {
    #pragma unroll
    for (int mi = 0; mi < 2; ++mi) {
      #pragma unroll
      for (int ni = 0; ni < 8; ++ni) {
        long col = (long)bn * 128 + ni * 16 + l16;
        #pragma unroll
        for (int i = 0; i < 4; ++i) {
          long row = (long)b * 4096 + bm * 128 + wave * 32 + mi * 16 + quad * 4 + i;
          Sf[row * 4096 + col] = acc[mi][ni][i];
        }
      }
    }
  }
}

// ---------------- av3 (modeA): fused rowstats + softmax + O = P @ vT^T ----------------
// grid(512), block 256 (4 waves). Per block: M=32 rows, N=256 cols, K=4096, BK=64.
// V staged via LDS; per-thread register prefetch of next tile (S + 8 V chunks).
// 2 blocks/CU -> independent barrier domains overlap stage/MFMA phases.
__global__ __launch_bounds__(256, 2) void gemm_av3(const h16* __restrict__ S,
                                                   const h16* __restrict__ vT,
                                                   const float2* __restrict__ stats,
                                                   float* __restrict__ attn,
                                                   h16* __restrict__ oh) {
  __shared__ h16 As[32][72];
  __shared__ h16 Bs[256][72];
  __shared__ float2 rs[32];
  const int tid = threadIdx.x;
  const int wave = tid >> 6, lane = tid & 63;
  const int quad = lane >> 4, l16 = lane & 15;
  const int mb = blockIdx.x;
  const long row0 = (long)mb * 32;
  const int b = mb >> 7;
  const h16* Vb = vT + (long)b * 256 * 4096;

  // ---- fused rowstats: merge 32 tile-stats per row -> (m, 1/l) for 32 rows ----
  {
    int r = tid >> 3, j = tid & 7;
    const float2* sp = stats + (row0 + r) * 32 + j * 4;
    float2 sv4[4];
    float m = -1e30f;
    #pragma unroll
    for (int t = 0; t < 4; ++t) { sv4[t] = sp[t]; m = fmaxf(m, sv4[t].x); }
    m = fmaxf(m, __shfl_xor(m, 1));
    m = fmaxf(m, __shfl_xor(m, 2));
    m = fmaxf(m, __shfl_xor(m, 4));
    float e = 0.0f;
    #pragma unroll
    for (int t = 0; t < 4; ++t) e += sv4[t].y * __expf(sv4[t].x - m);
    e += __shfl_xor(e, 1);
    e += __shfl_xor(e, 2);
    e += __shfl_xor(e, 4);
    if (j == 0) rs[r] = make_float2(m, 1.0f / e);
  }
  __syncthreads();

  const int sr = tid >> 3, sc = (tid & 7) * 8;   // 8 threads/row, h16x8 chunk
  const long srow = row0 + sr;
  const float2 st = rs[sr];
  const h16* Srow = S + srow * 4096;
  float* Arow = attn + srow * 4096;
  const int vr = tid >> 3;                       // V row base (0..31), +32p covers 256

  f32x4 acc[2][4] = {};

  // ---- prologue: prefetch k0=0 operands into registers ----
  h16x8 sv = *(const h16x8*)&Srow[sc];
  h16x8 bv[8];
  #pragma unroll
  for (int p = 0; p < 8; ++p)
    bv[p] = *(const h16x8*)&Vb[(long)(vr + 32 * p) * 4096 + sc];

  for (int k0 = 0; k0 < 4096; k0 += 64) {
    // ---- stage: p = exp(s-m)*invl, write attn (nontemporal), As/Bs to LDS ----
    float p[8];
    #pragma unroll
    for (int e = 0; e < 8; ++e) p[e] = __expf((float)sv[e] - st.x) * st.y;
    f32x4 w0 = {p[0], p[1], p[2], p[3]}, w1 = {p[4], p[5], p[6], p[7]};
    __builtin_nontemporal_store(w0, (f32x4*)&Arow[k0 + sc]);
    __builtin_nontemporal_store(w1, (f32x4*)&Arow[k0 + sc + 4]);
    h16x8 ph = {(h16)p[0], (h16)p[1], (h16)p[2], (h16)p[3],
                (h16)p[4], (h16)p[5], (h16)p[6], (h16)p[7]};
    *(h16x8*)&As[sr][sc] = ph;
    #pragma unroll
    for (int q = 0; q < 8; ++q)
      *(h16x8*)&Bs[vr + 32 * q][sc] = bv[q];
    // ---- prefetch next tile into registers (in flight during MFMA) ----
    int kn = k0 + 64;
    if (kn < 4096) {
      sv = *(const h16x8*)&Srow[kn + sc];
      #pragma unroll
      for (int q = 0; q < 8; ++q)
        bv[q] = *(const h16x8*)&Vb[(long)(vr + 32 * q) * 4096 + kn + sc];
    }
    __syncthreads();
    // ---- MFMA over this BK=64 tile ----
    #pragma unroll
    for (int ks = 0; ks < 64; ks += 32) {
      h16x8 a[2], bb[4];
      #pragma unroll
      for (int mi = 0; mi < 2; ++mi)
        a[mi] = *(const h16x8*)&As[mi * 16 + l16][ks + quad * 8];
      #pragma unroll
      for (int ni = 0; ni < 4; ++ni)
        bb[ni] = *(const h16x8*)&Bs[wave * 64 + ni * 16 + l16][ks + quad * 8];
      #pragma unroll
      for (int mi = 0; mi < 2; ++mi)
        #pragma unroll
        for (int ni = 0; ni < 4; ++ni)
          acc[mi][ni] = mfma16(a[mi], bb[ni], acc[mi][ni]);
    }
    __syncthreads();
  }
  // ---- epilogue: restage 32x256 O tile, coalesced h16x8 stores ----
  h16* stg = &Bs[0][0];   // 32*264 = 8448 h16 <= 256*72 = 18432
  const int SW = 264;
  #pragma unroll
  for (int mi = 0; mi < 2; ++mi) {
    #pragma unroll
    for (int ni = 0; ni < 4; ++ni) {
      int col = wave * 64 + ni * 16 + l16;
      #pragma unroll
      for (int i = 0; i < 4; ++i)
        stg[(mi * 16 + quad * 4 + i) * SW + col] = (h16)acc[mi][ni][i];
    }
  }
  __syncthreads();
  #pragma unroll
  for (int p = 0; p < 4; ++p) {
    int r = tid >> 3;
    int c = (tid & 7) * 8 + p * 64;
    h16x8 v = *(const h16x8*)&stg[r * SW + c];
    *(h16x8*)&oh[(row0 + r) * 256 + c] = v;
  }
}

// ---------------- av (modeB fallback, fp32 S in attn buffer, in-place) ----------------
// grid(256), block 512 (8 waves). Tile M=64, N=256, BK=64.
template <typename TS>
__global__ __launch_bounds__(512, 2) void gemm_av(const TS* __restrict__ S,
                                                  const h16* __restrict__ vT,
                                                  const float2* __restrict__ stats,
                                                  float* __restrict__ attn,
                                                  h16* __restrict__ oh) {
  __shared__ h16 As[64][72];
  __shared__ h16 Bs[256][72];
  __shared__ float2 rs[64];
  const int tid = threadIdx.x;
  const int wave = tid >> 6, lane = tid & 63;
  const int quad = lane >> 4, l16 = lane & 15;
  const int mb = blockIdx.x;
  const long row0 = (long)mb * 64;
  const int b = mb >> 6;
  const h16* Vb = vT + (long)b * 256 * 4096;

  {
    int r = tid >> 3, j = tid & 7;
    const float2* sp = stats + (row0 + r) * 32 + j * 4;
    float2 sv4[4];
    float m = -1e30f;
    #pragma unroll
    for (int t = 0; t < 4; ++t) { sv4[t] = sp[t]; m = fmaxf(m, sv4[t].x); }
    m = fmaxf(m, __shfl_xor(m, 1));
    m = fmaxf(m, __shfl_xor(m, 2));
    m = fmaxf(m, __shfl_xor(m, 4));
    float e = 0.0f;
    #pragma unroll
    for (int t = 0; t < 4; ++t) e += sv4[t].y * __expf(sv4[t].x - m);
    e += __shfl_xor(e, 1);
    e += __shfl_xor(e, 2);
    e += __shfl_xor(e, 4);
    if (j == 0) rs[r] = make_float2(m, 1.0f / e);
  }
  __syncthreads();

  const int sr = tid >> 3, sc = (tid & 7) * 8;
  const long srow = row0 + sr;
  const float2 st = rs[sr];
  const TS* Srow = S + srow * 4096;
  float* Arow = attn + srow * 4096;
  const int vd = tid >> 3;

  f32x4 acc[4][2] = {};

  h16x8 sv; float4 sa, sb;
  h16x8 bv0, bv1, bv2, bv3;
  if constexpr (sizeof(TS) == 2) {
    sv = *(const h16x8*)&Srow[sc];
  } else {
    sa = *(const float4*)&Srow[sc];
    sb = *(const float4*)&Srow[sc + 4];
  }
  bv0 = *(const h16x8*)&Vb[(long)(vd)       * 4096 + sc];
  bv1 = *(const h16x8*)&Vb[(long)(vd + 64)  * 4096 + sc];
  bv2 = *(const h16x8*)&Vb[(long)(vd + 128) * 4096 + sc];
  bv3 = *(const h16x8*)&Vb[(long)(vd + 192) * 4096 + sc];

  for (int k0 = 0; k0 < 4096; k0 += 64) {
    float p[8];
    if constexpr (sizeof(TS) == 2) {
      #pragma unroll
      for (int e = 0; e < 8; ++e) p[e] = __expf((float)sv[e] - st.x) * st.y;
    } else {
      p[0] = __expf(sa.x - st.x) * st.y; p[1] = __expf(sa.y - st.x) * st.y;
      p[2] = __expf(sa.z - st.x) * st.y; p[3] = __expf(sa.w - st.x) * st.y;
      p[4] = __expf(sb.x - st.x) * st.y; p[5] = __expf(sb.y - st.x) * st.y;
      p[6] = __expf(sb.z - st.x) * st.y; p[7] = __expf(sb.w - st.x) * st.y;
    }
    f32x4 w0 = {p[0], p[1], p[2], p[3]}, w1 = {p[4], p[5], p[6], p[7]};
    __builtin_nontemporal_store(w0, (f32x4*)&Arow[k0 + sc]);
    __builtin_nontemporal_store(w1, (f32x4*)&Arow[k0 + sc + 4]);
    h16x8 ph = {(h16)p[0], (h16)p[1], (h16)p[2], (h16)p[3],
                (h16)p[4], (h16)p[5], (h16)p[6], (h16)p[7]};
    *(h16x8*)&As[sr][sc] = ph;
    *(h16x8*)&Bs[vd][sc]       = bv0;
    *(h16x8*)&Bs[vd + 64][sc]  = bv1;
    *(h16x8*)&Bs[vd + 128][sc] = bv2;
    *(h16x8*)&Bs[vd + 192][sc] = bv3;
    int kn = k0 + 64;
    if (kn < 4096) {
      if constexpr (sizeof(TS) == 2) {
        sv = *(const h16x8*)&Srow[kn + sc];
      } else {
        sa = *(const float4*)&Srow[kn + sc];
        sb = *(const float4*)&Srow[kn + sc + 4];
      }
      bv0 = *(const h16x8*)&Vb[(long)(vd)       * 4096 + kn + sc];
      bv1 = *(const h16x8*)&Vb[(long)(vd + 64)  * 4096 + kn + sc];
      bv2 = *(const h16x8*)&Vb[(long)(vd + 128) * 4096 + kn + sc];
      bv3 = *(const h16x8*)&Vb[(long)(vd + 192) * 4096 + kn + sc];
    }
    __syncthreads();
    #pragma unroll
    for (int ks = 0; ks < 64; ks += 32) {
      h16x8 a[4], bbv[2];
      #pragma unroll
      for (int mi = 0; mi < 4; ++mi)
        a[mi] = *(const h16x8*)&As[mi * 16 + l16][ks + quad * 8];
      #pragma unroll
      for (int ni = 0; ni < 2; ++ni)
        bbv[ni] = *(const h16x8*)&Bs[wave * 32 + ni * 16 + l16][ks + quad * 8];
      #pragma unroll
      for (int mi = 0; mi < 4; ++mi)
        #pragma unroll
        for (int ni = 0; ni < 2; ++ni)
          acc[mi][ni] = mfma16(a[mi], bbv[ni], acc[mi][ni]);
    }
    __syncthreads();
  }
  h16* stg = &Bs[0][0];
  const int SW = 264;
  #pragma unroll
  for (int mi = 0; mi < 4; ++mi) {
    #pragma unroll
    for (int ni = 0; ni < 2; ++ni) {
      int col = wave * 32 + ni * 16 + l16;
      #pragma unroll
      for (int i = 0; i < 4; ++i) {
        int r = mi * 16 + quad * 4 + i;
        stg[r * SW + col] = (h16)acc[mi][ni][i];
      }
    }
  }
  __syncthreads();
  #pragma unroll
  for (int p = 0; p < 4; ++p) {
    int r = tid >> 3;
    int c = (tid & 7) * 8 + p * 64;
    h16x8 v = *(const h16x8*)&stg[r * SW + c];
    *(h16x8*)&oh[(row0 + r) * 256 + c] = v;
  }
}

extern "C" void kernel_launch(void* const* d_in, const int* in_sizes, int n_in,
                              void* d_out, int out_size, void* d_ws, size_t ws_size,
                              hipStream_t stream) {
  (void)in_sizes; (void)n_in; (void)out_size;
  const float* x   = (const float*)d_in[0];
  const float* qry = (const float*)d_in[1];
  const float* Wq  = (const float*)d_in[2];  const float* bq = (const float*)d_in[3];
  const float* Wk  = (const float*)d_in[4];  const float* bk = (const float*)d_in[5];
  const float* Wv  = (const float*)d_in[6];  const float* bv = (const float*)d_in[7];
  const float* W1  = (const float*)d_in[8];  const float* b1 = (const float*)d_in[9];
  const float* W2  = (const float*)d_in[10]; const float* b2 = (const float*)d_in[11];
  const float* W3  = (const float*)d_in[12]; const float* b3 = (const float*)d_in[13];

  float* outH = (float*)d_out;
  float* attn = outH + NQD;

  char* w = (char*)d_ws;
  h16* qh = (h16*)w;
  h16* kh = qh + NQD;
  h16* vT = kh + NQD;
  h16* oh = vT + NQD;
  h16* h1 = oh + NQD;
  h16* h2 = h1 + NQD;
  h16* wh = h2 + NQD;                               // 6 x 65536 h16
  size_t off_rs   = (size_t)(6 * NQD + 6 * 65536) * 2;   // 51,118,080
  size_t BASE     = off_rs + NROWS * 8;                  // 51,249,152
  size_t statsB   = NROWS * 32 * 8;                      // 4 MiB
  size_t ShB      = NROWS * NKK * 2;                     // 128 MiB

  bool modeA = ws_size >= BASE + statsB + ShB;
  bool modeB = !modeA && ws_size >= BASE + statsB;

  float2* stats = (modeA || modeB) ? (float2*)(w + BASE) : (float2*)h1;
  h16*    Sh    = modeA ? (h16*)(w + BASE + statsB) : nullptr;

  cast_weights<<<dim3(64, 6), 256, 0, stream>>>(Wq, Wk, Wv, W1, W2, W3, wh);
  qkv_proj<<<dim3(128, 4, 3), 256, 0, stream>>>(x, qry, wh, bq, bk, bv, qh, kh, vT);
  gemm_scores<<<dim3(32, 32, 4), 256, 0, stream>>>(qh, kh, stats, Sh, modeA ? nullptr : attn);
  if (modeA)
    gemm_av3<<<dim3(512), 256, 0, stream>>>(Sh, vT, stats, attn, oh);
  else
    gemm_av<float><<<dim3(256), 512, 0, stream>>>(attn, vT, stats, attn, oh);
  gemm256<<<dim3(128, 4), 256, 0, stream>>>(oh, wh + 3 * 65536, b1, h1, nullptr);
  gemm256<<<dim3(128, 4), 256, 0, stream>>>(h1, wh + 4 * 65536, b2, h2, nullptr);
  gemm256<<<dim3(128, 4), 256, 0, stream>>>(h2, wh + 5 * 65536, b3, nullptr, outH);
}